// Round 7
// baseline (1321.523 us; speedup 1.0000x reference)
//
#include <hip/hip_runtime.h>

// ---------------- problem constants ----------------
static constexpr int kV = 32000, kT = 1024, kC = 768, kH = 12, kL = 6, kB = 4;
static constexpr int kF = 3072;            // 4*C
static constexpr int kM = kB * kT;         // 4096 activation rows
static constexpr float kNEG = -30000.f;    // softmax mask sentinel (finite, exp()->0)

typedef __attribute__((ext_vector_type(8))) __bf16 bf16x8;
typedef __attribute__((ext_vector_type(4))) float  f32x4;

#define DEV __device__ __forceinline__

// async global->LDS, 16B per lane; LDS dest is wave-uniform base, HW adds lane*16.
DEV void gload16(const void* g, void* l) {
  __builtin_amdgcn_global_load_lds((__attribute__((address_space(1))) void*)(g),
                                   (__attribute__((address_space(3))) void*)(l), 16, 0, 0);
}

// ---------------- embedding ----------------
__global__ __launch_bounds__(192) void embed_k(const int* __restrict__ tokens,
                                               const float* __restrict__ tok_emb,
                                               const float* __restrict__ pos_emb,
                                               float* __restrict__ x) {
  int row = blockIdx.x, tid = threadIdx.x;
  int tok = tokens[row];
  int t   = row & (kT - 1);
  const float4* te = (const float4*)(tok_emb + (size_t)tok * kC);
  const float4* pe = (const float4*)(pos_emb + (size_t)t * kC);
  float4 a = te[tid], p = pe[tid];
  float4 r; r.x = a.x + p.x; r.y = a.y + p.y; r.z = a.z + p.z; r.w = a.w + p.w;
  ((float4*)(x + (size_t)row * kC))[tid] = r;
}

// ---------------- layernorm (fp32 in, bf16 out), vectorized ----------------
// 192 threads x float4 (768 = 192*4); ushort4 packed bf16 store (512B/wave/inst).
__global__ __launch_bounds__(192) void ln_k(const float* __restrict__ x,
                                            const float* __restrict__ g,
                                            const float* __restrict__ b,
                                            __bf16* __restrict__ out) {
  int row = blockIdx.x, tid = threadIdx.x;
  float4 v = ((const float4*)(x + (size_t)row * kC))[tid];
  float s = v.x + v.y + v.z + v.w;
#pragma unroll
  for (int m = 1; m < 64; m <<= 1) s += __shfl_xor(s, m, 64);
  __shared__ float red1[3], red2[3];
  int wid = tid >> 6;
  if ((tid & 63) == 0) red1[wid] = s;
  __syncthreads();
  float mu = (red1[0] + red1[1] + red1[2]) * (1.f / kC);
  float d0 = v.x - mu, d1 = v.y - mu, d2 = v.z - mu, d3 = v.w - mu;
  float q = d0 * d0 + d1 * d1 + d2 * d2 + d3 * d3;
#pragma unroll
  for (int m = 1; m < 64; m <<= 1) q += __shfl_xor(q, m, 64);
  if ((tid & 63) == 0) red2[wid] = q;
  __syncthreads();
  float var = (red2[0] + red2[1] + red2[2]) * (1.f / kC);
  float rs = rsqrtf(var + 1e-5f);
  float4 gv = ((const float4*)g)[tid];
  float4 bv = ((const float4*)b)[tid];
  float o0 = d0 * rs * gv.x + bv.x;
  float o1 = d1 * rs * gv.y + bv.y;
  float o2 = d2 * rs * gv.z + bv.z;
  float o3 = d3 * rs * gv.w + bv.w;
  ushort4 pk;
  unsigned short* pp = (unsigned short*)&pk;
  __bf16 t0 = (__bf16)o0; pp[0] = *(unsigned short*)&t0;
  __bf16 t1 = (__bf16)o1; pp[1] = *(unsigned short*)&t1;
  __bf16 t2 = (__bf16)o2; pp[2] = *(unsigned short*)&t2;
  __bf16 t3 = (__bf16)o3; pp[3] = *(unsigned short*)&t3;
  ((ushort4*)(out + (size_t)row * kC))[tid] = pk;
}

// ------------ weight fp32 [R][Cc] -> bf16 transposed [Cc][R]; z = layer ----------
// Write phase: 16x16 remap, ushort2 packed stores (2 cols/thread).
__global__ __launch_bounds__(256) void convT_k(const float* __restrict__ in,
                                               __bf16* __restrict__ out,
                                               int R, int Cc, size_t in_ls, size_t out_ls) {
  __shared__ float tile[32][33];
  const float* inp  = in  + (size_t)blockIdx.z * in_ls;
  __bf16*      outp = out + (size_t)blockIdx.z * out_ls;
  int r0 = blockIdx.y * 32, c0 = blockIdx.x * 32;
  int tx = threadIdx.x & 31, ty = threadIdx.x >> 5;   // 32 x 8 read map
#pragma unroll
  for (int i = 0; i < 32; i += 8)
    tile[ty + i][tx] = inp[(size_t)(r0 + ty + i) * Cc + c0 + tx];
  __syncthreads();
  int wx = threadIdx.x & 15, wy = threadIdx.x >> 4;   // 16 x 16 write map
#pragma unroll
  for (int i = 0; i < 32; i += 16) {
    int oc = wy + i;                                  // out row (input col c0+oc)
    __bf16 a = (__bf16)tile[wx * 2][oc];
    __bf16 c = (__bf16)tile[wx * 2 + 1][oc];
    ushort2 pk;
    unsigned short* pp = (unsigned short*)&pk;
    pp[0] = *(unsigned short*)&a;
    pp[1] = *(unsigned short*)&c;
    *(ushort2*)(&outp[(size_t)(c0 + oc) * R + r0 + wx * 2]) = pk;
  }
}

// ------------ fused q/k/v weight transpose: z = layer*3 + which ------------------
__global__ __launch_bounds__(256) void convT3_k(const float* __restrict__ wq,
                                                const float* __restrict__ wk,
                                                const float* __restrict__ wv,
                                                __bf16* __restrict__ qkvT) {
  __shared__ float tile[32][33];
  int z = blockIdx.z, layer = z / 3, which = z % 3;
  const float* inp = (which == 0 ? wq : which == 1 ? wk : wv) + (size_t)layer * kC * kC;
  __bf16* outp = qkvT + (size_t)layer * 3 * kC * kC + (size_t)which * kC * kC;
  int r0 = blockIdx.y * 32, c0 = blockIdx.x * 32;
  int tx = threadIdx.x & 31, ty = threadIdx.x >> 5;
#pragma unroll
  for (int i = 0; i < 32; i += 8)
    tile[ty + i][tx] = inp[(size_t)(r0 + ty + i) * kC + c0 + tx];
  __syncthreads();
  int wx = threadIdx.x & 15, wy = threadIdx.x >> 4;
#pragma unroll
  for (int i = 0; i < 32; i += 16) {
    int oc = wy + i;
    __bf16 a = (__bf16)tile[wx * 2][oc];
    __bf16 c = (__bf16)tile[wx * 2 + 1][oc];
    ushort2 pk;
    unsigned short* pp = (unsigned short*)&pk;
    pp[0] = *(unsigned short*)&a;
    pp[1] = *(unsigned short*)&c;
    *(ushort2*)(&outp[(size_t)(c0 + oc) * kC + r0 + wx * 2]) = pk;
  }
}

// 2D-chunked XCD tile decomposition (HK chiplet_transform_chunked mechanism).
DEV void tile_decode(int gx, int gy, int& mt, int& nt) {
  int nwg  = gx * gy;
  int wgid = blockIdx.y * gx + blockIdx.x;
  int q8 = nwg >> 3;
  int xcd = wgid & 7, loc = wgid >> 3;
  int sid = xcd * q8 + loc;                   // contiguous chunk per XCD
  int band = gx << 3;                         // 8 m-panels x all n
  int c = sid / band, rem = sid % band;
  nt = rem >> 3;
  mt = (c << 3) + (rem & 7);
}

// ---------------- gemmHD: 256x256 tile, 8 waves (2Mx4N), 2-barrier/K-tile pipe ----
// f32 out + bias (LM head). LDS 128KB; chunked XCD decode.
// Measured-best LM-head structure: 256² AI halves L2/L3 traffic vs 128²
// (R5: gemm128-based LM head was +20us; R0: BK=32 ring was +20us).
__global__ __launch_bounds__(512, 1) void gemmHD_k(const __bf16* __restrict__ A,
                                                   const __bf16* __restrict__ Bt,
                                                   const float* __restrict__ bias,
                                                   float* __restrict__ Cout,
                                                   int M, int N, int K) {
  __shared__ char lds[131072];
  int tid = threadIdx.x, lane = tid & 63, wid = tid >> 6;
  int wm = wid >> 2, wn = wid & 3;            // 2 x 4 waves, each 128x64 output
  int mt, ntile;
  tile_decode(gridDim.x, gridDim.y, mt, ntile);
  int m0 = mt * 256, n0 = ntile * 256;
  int fr = lane & 15, fg = lane >> 4;
  f32x4 acc[8][4] = {};
  const size_t ldab = (size_t)K * 2;
  int nt = K >> 6;

  auto STAGE = [&](char* base, int t) {       // 8 gloads/thread (A 32KB + B 32KB)
    int k0 = t << 6;
#pragma unroll
    for (int it = 0; it < 4; ++it) {
      int oo  = tid * 16 + it * 8192;
      int row = oo >> 7;
      int cb  = (oo & 127) ^ ((row & 7) << 4);
      gload16((const char*)A + (size_t)(m0 + row) * ldab + (size_t)k0 * 2 + cb,
              base + it * 8192 + wid * 1024);
    }
#pragma unroll
    for (int it = 0; it < 4; ++it) {
      int oo  = tid * 16 + it * 8192;
      int row = oo >> 7;
      int cb  = (oo & 127) ^ ((row & 7) << 4);
      gload16((const char*)Bt + (size_t)(n0 + row) * ldab + (size_t)k0 * 2 + cb,
              base + 32768 + it * 8192 + wid * 1024);
    }
  };

  STAGE(lds, 0);
  asm volatile("s_waitcnt vmcnt(0)" ::: "memory");
  __builtin_amdgcn_sched_barrier(0);
  __builtin_amdgcn_s_barrier();

  for (int t = 0; t < nt; ++t) {
    char* base = lds + (t & 1) * 65536;
    const char* Ab = base;
    const char* Bb = base + 32768;
    if (t + 1 < nt) STAGE(lds + ((t + 1) & 1) * 65536, t + 1);

    __builtin_amdgcn_s_setprio(1);
    bf16x8 bfr[4];
#pragma unroll
    for (int p = 0; p < 4; ++p) {
      const int ks = p >> 1, mh = p & 1;
      const int cc = ks * 64 + fg * 16;
      if (mh == 0) {
#pragma unroll
        for (int n = 0; n < 4; ++n) {
          int row = wn * 64 + n * 16 + fr;
          bfr[n] = *(const bf16x8*)(Bb + row * 128 + (cc ^ ((row & 7) << 4)));
        }
      }
      bf16x8 af[4];
#pragma unroll
      for (int i = 0; i < 4; ++i) {
        int row = wm * 128 + mh * 64 + i * 16 + fr;
        af[i] = *(const bf16x8*)(Ab + row * 128 + (cc ^ ((row & 7) << 4)));
      }
#pragma unroll
      for (int i = 0; i < 4; ++i)
#pragma unroll
        for (int n = 0; n < 4; ++n)
          acc[mh * 4 + i][n] = __builtin_amdgcn_mfma_f32_16x16x32_bf16(
              af[i], bfr[n], acc[mh * 4 + i][n], 0, 0, 0);
    }
    __builtin_amdgcn_s_setprio(0);

    __builtin_amdgcn_s_barrier();             // all waves done reading buf[t&1]
    if (t + 1 < nt)
      asm volatile("s_waitcnt vmcnt(0)" ::: "memory");  // t+1 landed (covered)
    __builtin_amdgcn_sched_barrier(0);
    __builtin_amdgcn_s_barrier();             // t+1 visible to all waves
  }

  // epilogue; D layout: col = lane&15, row = (lane>>4)*4 + reg
#pragma unroll
  for (int mi = 0; mi < 8; ++mi) {
#pragma unroll
    for (int n = 0; n < 4; ++n) {
      int cg  = n0 + wn * 64 + n * 16 + fr;
      int rgb = m0 + wm * 128 + mi * 16 + fg * 4;
      float bv = bias[cg];
#pragma unroll
      for (int r = 0; r < 4; ++r)
        Cout[(size_t)(rgb + r) * N + cg] = acc[mi][n][r] + bv;
    }
  }
}

// ---------------- gemm64: 128x64 tile, 4 waves (2Mx2N), counted-vmcnt pipeline ---
// R6 MEASURED: this structure (384+ blocks, 3 blocks/CU via 48KB LDS) beat
// under-subscribed gemm128 by 190us on the N=768 GEMMs — grid-vs-residency
// subscription is the dominant knob. Now also used for qkv (1152 blocks) and
// ff1 (1536 blocks = 2 perfectly balanced rounds of 768 slots).
// EPI: 1 = bf16 out, bias+relu; 2 = f32 out, bias+residual (res MAY alias Cout);
//      4 = qkv split (q,k -> Cout [M][1536]; v -> vT [768][kM] via `res`;
//          block-uniform region test since 1536 % 64 == 0).
template <int EPI>
__global__ __launch_bounds__(256) void gemm64_k(const __bf16* __restrict__ A,
                                                const __bf16* __restrict__ Bt,
                                                const float* __restrict__ bias,
                                                const float* res,
                                                void* Cout,
                                                int M, int N, int K) {
  __shared__ char lds[49152];                 // 2 x (A 16KB | B 8KB)
  int tid = threadIdx.x, lane = tid & 63, wid = tid >> 6;
  int wr = wid >> 1, wc = wid & 1;            // wave: 64 rows x 32 cols
  int mt, ntile;
  tile_decode(gridDim.x, gridDim.y, mt, ntile);
  int m0 = mt * 128, n0 = ntile * 64;
  int fr = lane & 15, fg = lane >> 4;
  f32x4 acc[4][2] = {};
  const size_t ldab = (size_t)K * 2;

  auto STAGE = [&](int buf, int t) {          // 6 vmem ops/thread
    int k0 = t << 6;
    char* base = lds + buf * 24576;
#pragma unroll
    for (int it = 0; it < 4; ++it) {          // A: 128 rows x 128B
      int oo  = tid * 16 + it * 4096;
      int row = oo >> 7;
      int cb  = (oo & 127) ^ ((row & 7) << 4);
      gload16((const char*)A + (size_t)(m0 + row) * ldab + (size_t)k0 * 2 + cb,
              base + it * 4096 + wid * 1024);
    }
#pragma unroll
    for (int it = 0; it < 2; ++it) {          // B: 64 rows x 128B
      int oo  = tid * 16 + it * 4096;
      int row = oo >> 7;
      int cb  = (oo & 127) ^ ((row & 7) << 4);
      gload16((const char*)Bt + (size_t)(n0 + row) * ldab + (size_t)k0 * 2 + cb,
              base + 16384 + it * 4096 + wid * 1024);
    }
  };
  auto COMPUTE = [&](int buf) {
    char* base = lds + buf * 24576;
#pragma unroll
    for (int kk = 0; kk < 2; ++kk) {
      int cb = (kk * 64 + (fg << 4)) ^ ((lane & 7) << 4);
      bf16x8 af[4], bfr[2];
#pragma unroll
      for (int i = 0; i < 4; ++i)
        af[i] = *(const bf16x8*)(base + (wr * 64 + i * 16 + fr) * 128 + cb);
#pragma unroll
      for (int j = 0; j < 2; ++j)
        bfr[j] = *(const bf16x8*)(base + 16384 + (wc * 32 + j * 16 + fr) * 128 + cb);
#pragma unroll
      for (int i = 0; i < 4; ++i)
#pragma unroll
        for (int j = 0; j < 2; ++j)
          acc[i][j] = __builtin_amdgcn_mfma_f32_16x16x32_bf16(af[i], bfr[j], acc[i][j], 0, 0, 0);
    }
  };

  int nt = K >> 6;
  STAGE(0, 0);
  STAGE(1, 1);
  asm volatile("s_waitcnt vmcnt(6)" ::: "memory");
  __builtin_amdgcn_sched_barrier(0);
  __builtin_amdgcn_s_barrier();
  int cur = 0;
  for (int t = 0; t < nt; ++t) {
    __builtin_amdgcn_s_setprio(1);
    COMPUTE(cur);
    __builtin_amdgcn_s_setprio(0);
    if (t + 1 < nt) {
      __builtin_amdgcn_s_barrier();
      if (t + 2 < nt) {
        STAGE(cur, t + 2);
        asm volatile("s_waitcnt vmcnt(6)" ::: "memory");
      } else {
        asm volatile("s_waitcnt vmcnt(0)" ::: "memory");
      }
      __builtin_amdgcn_sched_barrier(0);
      __builtin_amdgcn_s_barrier();
      cur ^= 1;
    }
  }

#pragma unroll
  for (int i = 0; i < 4; ++i) {
#pragma unroll
    for (int j = 0; j < 2; ++j) {
      int cg  = n0 + wc * 32 + j * 16 + fr;
      int rgb = m0 + wr * 64 + i * 16 + fg * 4;
      if constexpr (EPI == 4) {
        if (n0 < 1536) {                       // q,k region (block-uniform)
#pragma unroll
          for (int r = 0; r < 4; ++r)
            ((__bf16*)Cout)[(size_t)(rgb + r) * 1536 + cg] = (__bf16)acc[i][j][r];
        } else {                               // v region -> vT [768][kM]
          int d = cg - 1536;
          ushort4 pk;
          unsigned short* pp = (unsigned short*)&pk;
#pragma unroll
          for (int r = 0; r < 4; ++r) {
            __bf16 bv = (__bf16)acc[i][j][r];
            pp[r] = *(unsigned short*)&bv;
          }
          __bf16* vT = (__bf16*)const_cast<float*>(res);
          *(ushort4*)(vT + (size_t)d * kM + rgb) = pk;
        }
      } else if constexpr (EPI == 1) {
        float bv = bias[cg];
#pragma unroll
        for (int r = 0; r < 4; ++r) {
          float v = acc[i][j][r] + bv;
          ((__bf16*)Cout)[(size_t)(rgb + r) * N + cg] = (__bf16)fmaxf(v, 0.f);
        }
      } else {
        float bv = bias[cg];
#pragma unroll
        for (int r = 0; r < 4; ++r) {
          float v = acc[i][j][r] + bv;
          size_t idx = (size_t)(rgb + r) * N + cg;
          ((float*)Cout)[idx] = v + res[idx];
        }
      }
    }
  }
}

// ---------------- flash attention: double-buffered K/V, 1 barrier/tile, T14 ------
// qk: bf16 [4096][1536], vT: bf16 [768][4096] (cols = global rows).
// LDS: buf0 K/V 16KB | buf1 K/V 16KB | P 4x2KB = 40KB -> 4 blocks/CU.
// Per tile: sync; write LDS[cur^1]=regs(st+1); issue loads(st+2); compute(cur).
// qt DECORRELATION: work ~ (qt+1); co-resident blocks on one CU are
// {wgid, wgid+256, wgid+512} and 256 % 16 == 0, so qt=blockIdx.x gives every
// CU three SAME-qt blocks (makespan 48 units vs 25.5 avg, ~53% eff).
// Rotate qt per (hh,bb) plane so co-resident triples become {x,x+5,x+10}:
// worst CU sum 33 vs avg 28.5 -> ~86% eff. Bijective in x per plane.
__global__ __launch_bounds__(256) void attn_k(const __bf16* __restrict__ qk,
                                              const __bf16* __restrict__ vT,
                                              __bf16* __restrict__ optr) {
  __shared__ char lds[40960];
  int tid = threadIdx.x, lane = tid & 63, wid = tid >> 6;
  int hh = blockIdx.y, bb = blockIdx.z;
  int zy = bb * 12 + hh;                      // 0..47; co-resident triples differ by 16
  int qt = (blockIdx.x + (zy >> 4) * 5 + (zy & 15)) & 15;
  size_t rowbase = (size_t)bb * kT;
  int qr = qt * 64 + wid * 16;
  char* Psw = lds + 32768 + wid * 2048;

  bf16x8 qf[2];
  {
    const __bf16* p = qk + (rowbase + qr + (lane & 15)) * (2 * kC) + hh * 64 + ((lane >> 4) * 8);
    qf[0] = *(const bf16x8*)p;
    qf[1] = *(const bf16x8*)(p + 32);
  }
  f32x4 oacc[4] = {};
  float mrun[4] = {kNEG, kNEG, kNEG, kNEG};
  float lrun[4] = {0.f, 0.f, 0.f, 0.f};

  bf16x8 kr[2], vr[2];
  auto LOADT = [&](int st) {                  // global -> regs (pre-swizzled slots)
    int s0 = st * 64;
#pragma unroll
    for (int it = 0; it < 2; ++it) {
      int oo  = tid * 16 + it * 4096;
      int row = oo >> 7;
      int cb  = (oo & 127) ^ ((row & 7) << 4);
      kr[it] = *(const bf16x8*)((const char*)qk +
                 ((rowbase + s0 + row) * (2 * kC) + kC + hh * 64) * 2 + cb);
      vr[it] = *(const bf16x8*)((const char*)vT +
                 ((size_t)(hh * 64 + row) * kM + rowbase + s0) * 2 + cb);
    }
  };
  auto WRITET = [&](int buf) {                // regs -> LDS[buf]
    char* b = lds + buf * 16384;
#pragma unroll
    for (int it = 0; it < 2; ++it) {
      int oo = tid * 16 + it * 4096;
      *(bf16x8*)(b + oo)        = kr[it];
      *(bf16x8*)(b + 8192 + oo) = vr[it];
    }
  };

  LOADT(0);
  WRITET(0);
  if (qt >= 1) LOADT(1);

  for (int st = 0; st <= qt; ++st) {
    int cur = st & 1;
    char* kb = lds + cur * 16384;
    char* vb = kb + 8192;
    __syncthreads();                          // prev compute done; own writes drained
    if (st + 1 <= qt) {
      WRITET(cur ^ 1);                        // regs hold tile st+1
      if (st + 2 <= qt) LOADT(st + 2);        // issue early: full tile of cover
    }

    int s0 = st * 64;
    // S = Q K^T
    f32x4 sacc[4] = {};
#pragma unroll
    for (int kk = 0; kk < 2; ++kk) {
      int cb = (kk * 64 + ((lane >> 4) << 4)) ^ ((lane & 7) << 4);
#pragma unroll
      for (int j = 0; j < 4; ++j) {
        bf16x8 kf = *(const bf16x8*)(kb + (j * 16 + (lane & 15)) * 128 + cb);
        sacc[j] = __builtin_amdgcn_mfma_f32_16x16x32_bf16(qf[kk], kf, sacc[j], 0, 0, 0);
      }
    }

    // online softmax (row = qr + (lane>>4)*4 + r, col = s0 + j*16 + (lane&15))
    float pv[4][4], vm[4] = {kNEG, kNEG, kNEG, kNEG};
#pragma unroll
    for (int j = 0; j < 4; ++j) {
      int scol = s0 + j * 16 + (lane & 15);
#pragma unroll
      for (int r = 0; r < 4; ++r) {
        int qrow = qr + (lane >> 4) * 4 + r;
        float sv = sacc[j][r] * 0.125f;
        if (scol > qrow) sv = kNEG;
        pv[j][r] = sv;
        vm[r] = fmaxf(vm[r], sv);
      }
    }
#pragma unroll
    for (int r = 0; r < 4; ++r) {
      float v = vm[r];
      v = fmaxf(v, __shfl_xor(v, 1, 64)); v = fmaxf(v, __shfl_xor(v, 2, 64));
      v = fmaxf(v, __shfl_xor(v, 4, 64)); v = fmaxf(v, __shfl_xor(v, 8, 64));
      float mnew = fmaxf(mrun[r], v);
      float sc = __expf(mrun[r] - mnew);
      mrun[r] = mnew;
      lrun[r] *= sc;
      oacc[0][r] *= sc; oacc[1][r] *= sc; oacc[2][r] *= sc; oacc[3][r] *= sc;
      float rsum = 0.f;
#pragma unroll
      for (int j = 0; j < 4; ++j) {
        float p = __expf(pv[j][r] - mnew);
        pv[j][r] = p;
        rsum += p;
      }
      rsum += __shfl_xor(rsum, 1, 64); rsum += __shfl_xor(rsum, 2, 64);
      rsum += __shfl_xor(rsum, 4, 64); rsum += __shfl_xor(rsum, 8, 64);
      lrun[r] += rsum;
    }

    // P (D-layout regs) -> per-wave LDS (swizzled) as A-operand
#pragma unroll
    for (int j = 0; j < 4; ++j)
#pragma unroll
      for (int r = 0; r < 4; ++r) {
        int rloc = (lane >> 4) * 4 + r;
        int cbyt = (2 * (j * 16 + (lane & 15))) ^ ((rloc & 7) << 4);
        *(__bf16*)(Psw + rloc * 128 + cbyt) = (__bf16)pv[j][r];
      }

    // O += P @ V
#pragma unroll
    for (int kk = 0; kk < 2; ++kk) {
      int cb = (kk * 64 + ((lane >> 4) << 4)) ^ ((lane & 7) << 4);
      bf16x8 pf = *(const bf16x8*)(Psw + (lane & 15) * 128 + cb);
#pragma unroll
      for (int j = 0; j < 4; ++j) {
        bf16x8 vf = *(const bf16x8*)(vb + (j * 16 + (lane & 15)) * 128 + cb);
        oacc[j] = __builtin_amdgcn_mfma_f32_16x16x32_bf16(pf, vf, oacc[j], 0, 0, 0);
      }
    }
  }

#pragma unroll
  for (int r = 0; r < 4; ++r) {
    float inv = lrun[r] > 0.f ? 1.f / lrun[r] : 0.f;
#pragma unroll
    for (int j = 0; j < 4; ++j) {
      int cg = hh * 64 + j * 16 + (lane & 15);
      int rg = qr + (lane >> 4) * 4 + r;
      optr[(rowbase + rg) * kC + cg] = (__bf16)(oacc[j][r] * inv);
    }
  }
}

// ---------------- host ----------------
extern "C" void kernel_launch(void* const* d_in, const int* in_sizes, int n_in,
                              void* d_out, int out_size, void* d_ws, size_t ws_size,
                              hipStream_t stream) {
  (void)in_sizes; (void)n_in; (void)out_size; (void)ws_size;
  const int*   tokens  = (const int*)  d_in[0];
  const float* tok_emb = (const float*)d_in[1];
  const float* pos_emb = (const float*)d_in[2];
  const float* ln1_g   = (const float*)d_in[3];
  const float* ln1_b   = (const float*)d_in[4];
  const float* wq      = (const float*)d_in[5];
  const float* wk      = (const float*)d_in[6];
  const float* wv      = (const float*)d_in[7];
  const float* wo      = (const float*)d_in[8];
  const float* bo      = (const float*)d_in[9];
  const float* ln2_g   = (const float*)d_in[10];
  const float* ln2_b   = (const float*)d_in[11];
  const float* w1      = (const float*)d_in[12];
  const float* b1      = (const float*)d_in[13];
  const float* w2      = (const float*)d_in[14];
  const float* b2      = (const float*)d_in[15];
  const float* lnf_g   = (const float*)d_in[16];
  const float* lnf_b   = (const float*)d_in[17];
  const float* lm_w    = (const float*)d_in[18];
  const float* lm_b    = (const float*)d_in[19];
  float* out = (float*)d_out;

  char* ws = (char*)d_ws;
  size_t off = 0;
  auto alloc = [&](size_t bytes) -> char* {
    char* p = ws + off; off += (bytes + 255) & ~(size_t)255; return p;
  };
  float*  x    = (float*) alloc((size_t)kM * kC * 4);             // 12.6 MB
  __bf16* h    = (__bf16*)alloc((size_t)kM * kC * 2);             // 6.3 MB
  __bf16* qkvT = (__bf16*)alloc((size_t)kL * 3 * kC * kC * 2);    // 21.2 MB
  __bf16* woT  = (__bf16*)alloc((size_t)kL * kC * kC * 2);        //  7.1 MB
  __bf16* w1T  = (__bf16*)alloc((size_t)kL * kC * kF * 2);        // 28.3 MB
  __bf16* w2T  = (__bf16*)alloc((size_t)kL * kC * kF * 2);        // 28.3 MB
  __bf16* qkb  = (__bf16*)alloc((size_t)kM * 2 * kC * 2);         // 12.6 MB
  __bf16* vTb  = (__bf16*)alloc((size_t)kC * kM * 2);             // 6.3 MB
  __bf16* ob   = (__bf16*)alloc((size_t)kM * kC * 2);             // 6.3 MB
  __bf16* ffb  = (__bf16*)alloc((size_t)kM * kF * 2);             // 25.2 MB
  __bf16* lmwT = qkb;  // lm head transpose aliases qkb..ffb (50.4 >= 49.2 MB)

  dim3 blk(256), blk512(512);
  convT3_k<<<dim3(kC/32, kC/32, 3*kL), blk, 0, stream>>>(wq, wk, wv, qkvT);
  convT_k<<<dim3(kC/32, kC/32, kL), blk, 0, stream>>>(wo, woT, kC, kC, (size_t)kC*kC, (size_t)kC*kC);
  convT_k<<<dim3(kF/32, kC/32, kL), blk, 0, stream>>>(w1, w1T, kC, kF, (size_t)kC*kF, (size_t)kC*kF);
  convT_k<<<dim3(kC/32, kF/32, kL), blk, 0, stream>>>(w2, w2T, kF, kC, (size_t)kC*kF, (size_t)kC*kF);

  embed_k<<<kM, 192, 0, stream>>>(tokens, tok_emb, pos_emb, x);

  for (int l = 0; l < kL; ++l) {
    ln_k<<<kM, 192, 0, stream>>>(x, ln1_g + l*kC, ln1_b + l*kC, h);
    // q,k -> qkb [4096][1536]; v -> vTb [768][4096]; 36x32 = 1152 blocks @3/CU
    gemm64_k<4><<<dim3(3*kC/64, kM/128), blk, 0, stream>>>(
        h, qkvT + (size_t)l*3*kC*kC, nullptr, (const float*)vTb, qkb, kM, 3*kC, kC);
    attn_k<<<dim3(kT/64, kH, kB), blk, 0, stream>>>(qkb, vTb, ob);
    // x = o @ wo + bo + x (in-place residual), 384 blocks
    gemm64_k<2><<<dim3(kC/64, kM/128), blk, 0, stream>>>(ob, woT + (size_t)l*kC*kC, bo + l*kC, x, x, kM, kC, kC);
    ln_k<<<kM, 192, 0, stream>>>(x, ln2_g + l*kC, ln2_b + l*kC, h);
    // ff = relu(h @ w1 + b1); 48x32 = 1536 blocks = 2 balanced rounds @3/CU
    gemm64_k<1><<<dim3(kF/64, kM/128), blk, 0, stream>>>(h, w1T + (size_t)l*kC*kF, b1 + l*kF, nullptr, ffb, kM, kF, kC);
    // x = ff @ w2 + b2 + x, 384 blocks
    gemm64_k<2><<<dim3(kC/64, kM/128), blk, 0, stream>>>(ffb, w2T + (size_t)l*kC*kF, b2 + l*kC, x, x, kM, kC, kF);
  }
  convT_k<<<dim3(kV/32, kC/32, 1), blk, 0, stream>>>(lm_w, lmwT, kC, kV, 0, 0);
  ln_k<<<kM, 192, 0, stream>>>(x, lnf_g, lnf_b, h);
  // logits = h @ lm_w + lm_b  (2-barrier whole-tile 256² pipeline, fp32 out)
  gemmHD_k<<<dim3(kV/256, kM/256), blk512, 0, stream>>>(h, lmwT, lm_b, out, kM, kV, kC);
}

// Round 8
// 1228.912 us; speedup vs baseline: 1.0754x; 1.0754x over previous
//
#include <hip/hip_runtime.h>

// ---------------- problem constants ----------------
static constexpr int kV = 32000, kT = 1024, kC = 768, kH = 12, kL = 6, kB = 4;
static constexpr int kF = 3072;            // 4*C
static constexpr int kM = kB * kT;         // 4096 activation rows
static constexpr float kNEG = -30000.f;    // softmax mask sentinel (finite, exp()->0)

typedef __attribute__((ext_vector_type(8))) __bf16 bf16x8;
typedef __attribute__((ext_vector_type(4))) float  f32x4;

#define DEV __device__ __forceinline__

// async global->LDS, 16B per lane; LDS dest is wave-uniform base, HW adds lane*16.
DEV void gload16(const void* g, void* l) {
  __builtin_amdgcn_global_load_lds((__attribute__((address_space(1))) void*)(g),
                                   (__attribute__((address_space(3))) void*)(l), 16, 0, 0);
}

// ---------------- embedding ----------------
__global__ __launch_bounds__(192) void embed_k(const int* __restrict__ tokens,
                                               const float* __restrict__ tok_emb,
                                               const float* __restrict__ pos_emb,
                                               float* __restrict__ x) {
  int row = blockIdx.x, tid = threadIdx.x;
  int tok = tokens[row];
  int t   = row & (kT - 1);
  const float4* te = (const float4*)(tok_emb + (size_t)tok * kC);
  const float4* pe = (const float4*)(pos_emb + (size_t)t * kC);
  float4 a = te[tid], p = pe[tid];
  float4 r; r.x = a.x + p.x; r.y = a.y + p.y; r.z = a.z + p.z; r.w = a.w + p.w;
  ((float4*)(x + (size_t)row * kC))[tid] = r;
}

// ---------------- layernorm (fp32 in, bf16 out), vectorized ----------------
__global__ __launch_bounds__(192) void ln_k(const float* __restrict__ x,
                                            const float* __restrict__ g,
                                            const float* __restrict__ b,
                                            __bf16* __restrict__ out) {
  int row = blockIdx.x, tid = threadIdx.x;
  float4 v = ((const float4*)(x + (size_t)row * kC))[tid];
  float s = v.x + v.y + v.z + v.w;
#pragma unroll
  for (int m = 1; m < 64; m <<= 1) s += __shfl_xor(s, m, 64);
  __shared__ float red1[3], red2[3];
  int wid = tid >> 6;
  if ((tid & 63) == 0) red1[wid] = s;
  __syncthreads();
  float mu = (red1[0] + red1[1] + red1[2]) * (1.f / kC);
  float d0 = v.x - mu, d1 = v.y - mu, d2 = v.z - mu, d3 = v.w - mu;
  float q = d0 * d0 + d1 * d1 + d2 * d2 + d3 * d3;
#pragma unroll
  for (int m = 1; m < 64; m <<= 1) q += __shfl_xor(q, m, 64);
  if ((tid & 63) == 0) red2[wid] = q;
  __syncthreads();
  float var = (red2[0] + red2[1] + red2[2]) * (1.f / kC);
  float rs = rsqrtf(var + 1e-5f);
  float4 gv = ((const float4*)g)[tid];
  float4 bv = ((const float4*)b)[tid];
  float o0 = d0 * rs * gv.x + bv.x;
  float o1 = d1 * rs * gv.y + bv.y;
  float o2 = d2 * rs * gv.z + bv.z;
  float o3 = d3 * rs * gv.w + bv.w;
  ushort4 pk;
  unsigned short* pp = (unsigned short*)&pk;
  __bf16 t0 = (__bf16)o0; pp[0] = *(unsigned short*)&t0;
  __bf16 t1 = (__bf16)o1; pp[1] = *(unsigned short*)&t1;
  __bf16 t2 = (__bf16)o2; pp[2] = *(unsigned short*)&t2;
  __bf16 t3 = (__bf16)o3; pp[3] = *(unsigned short*)&t3;
  ((ushort4*)(out + (size_t)row * kC))[tid] = pk;
}

// ------------ weight fp32 [R][Cc] -> bf16 transposed [Cc][R]; z = layer ----------
__global__ __launch_bounds__(256) void convT_k(const float* __restrict__ in,
                                               __bf16* __restrict__ out,
                                               int R, int Cc, size_t in_ls, size_t out_ls) {
  __shared__ float tile[32][33];
  const float* inp  = in  + (size_t)blockIdx.z * in_ls;
  __bf16*      outp = out + (size_t)blockIdx.z * out_ls;
  int r0 = blockIdx.y * 32, c0 = blockIdx.x * 32;
  int tx = threadIdx.x & 31, ty = threadIdx.x >> 5;   // 32 x 8 read map
#pragma unroll
  for (int i = 0; i < 32; i += 8)
    tile[ty + i][tx] = inp[(size_t)(r0 + ty + i) * Cc + c0 + tx];
  __syncthreads();
  int wx = threadIdx.x & 15, wy = threadIdx.x >> 4;   // 16 x 16 write map
#pragma unroll
  for (int i = 0; i < 32; i += 16) {
    int oc = wy + i;                                  // out row (input col c0+oc)
    __bf16 a = (__bf16)tile[wx * 2][oc];
    __bf16 c = (__bf16)tile[wx * 2 + 1][oc];
    ushort2 pk;
    unsigned short* pp = (unsigned short*)&pk;
    pp[0] = *(unsigned short*)&a;
    pp[1] = *(unsigned short*)&c;
    *(ushort2*)(&outp[(size_t)(c0 + oc) * R + r0 + wx * 2]) = pk;
  }
}

// ------------ fused q/k/v weight transpose: z = layer*3 + which ------------------
__global__ __launch_bounds__(256) void convT3_k(const float* __restrict__ wq,
                                                const float* __restrict__ wk,
                                                const float* __restrict__ wv,
                                                __bf16* __restrict__ qkvT) {
  __shared__ float tile[32][33];
  int z = blockIdx.z, layer = z / 3, which = z % 3;
  const float* inp = (which == 0 ? wq : which == 1 ? wk : wv) + (size_t)layer * kC * kC;
  __bf16* outp = qkvT + (size_t)layer * 3 * kC * kC + (size_t)which * kC * kC;
  int r0 = blockIdx.y * 32, c0 = blockIdx.x * 32;
  int tx = threadIdx.x & 31, ty = threadIdx.x >> 5;
#pragma unroll
  for (int i = 0; i < 32; i += 8)
    tile[ty + i][tx] = inp[(size_t)(r0 + ty + i) * kC + c0 + tx];
  __syncthreads();
  int wx = threadIdx.x & 15, wy = threadIdx.x >> 4;
#pragma unroll
  for (int i = 0; i < 32; i += 16) {
    int oc = wy + i;
    __bf16 a = (__bf16)tile[wx * 2][oc];
    __bf16 c = (__bf16)tile[wx * 2 + 1][oc];
    ushort2 pk;
    unsigned short* pp = (unsigned short*)&pk;
    pp[0] = *(unsigned short*)&a;
    pp[1] = *(unsigned short*)&c;
    *(ushort2*)(&outp[(size_t)(c0 + oc) * kC + r0 + wx * 2]) = pk;
  }
}

// 2D-chunked XCD tile decomposition (HK chiplet_transform_chunked mechanism).
DEV void tile_decode(int gx, int gy, int& mt, int& nt) {
  int nwg  = gx * gy;
  int wgid = blockIdx.y * gx + blockIdx.x;
  int q8 = nwg >> 3;
  int xcd = wgid & 7, loc = wgid >> 3;
  int sid = xcd * q8 + loc;                   // contiguous chunk per XCD
  int band = gx << 3;                         // 8 m-panels x all n
  int c = sid / band, rem = sid % band;
  nt = rem >> 3;
  mt = (c << 3) + (rem & 7);
}

// ---------------- gemmHD: 256x256 tile, 8 waves (2Mx4N), 2-barrier/K-tile pipe ----
// f32 out + bias (LM head). LDS 128KB; chunked XCD decode. Measured-best LM-head
// structure (R5: 128² LM head +20us; R0: BK=32 ring +20us).
__global__ __launch_bounds__(512, 1) void gemmHD_k(const __bf16* __restrict__ A,
                                                   const __bf16* __restrict__ Bt,
                                                   const float* __restrict__ bias,
                                                   float* __restrict__ Cout,
                                                   int M, int N, int K) {
  __shared__ char lds[131072];
  int tid = threadIdx.x, lane = tid & 63, wid = tid >> 6;
  int wm = wid >> 2, wn = wid & 3;            // 2 x 4 waves, each 128x64 output
  int mt, ntile;
  tile_decode(gridDim.x, gridDim.y, mt, ntile);
  int m0 = mt * 256, n0 = ntile * 256;
  int fr = lane & 15, fg = lane >> 4;
  f32x4 acc[8][4] = {};
  const size_t ldab = (size_t)K * 2;
  int nt = K >> 6;

  auto STAGE = [&](char* base, int t) {       // 8 gloads/thread (A 32KB + B 32KB)
    int k0 = t << 6;
#pragma unroll
    for (int it = 0; it < 4; ++it) {
      int oo  = tid * 16 + it * 8192;
      int row = oo >> 7;
      int cb  = (oo & 127) ^ ((row & 7) << 4);
      gload16((const char*)A + (size_t)(m0 + row) * ldab + (size_t)k0 * 2 + cb,
              base + it * 8192 + wid * 1024);
    }
#pragma unroll
    for (int it = 0; it < 4; ++it) {
      int oo  = tid * 16 + it * 8192;
      int row = oo >> 7;
      int cb  = (oo & 127) ^ ((row & 7) << 4);
      gload16((const char*)Bt + (size_t)(n0 + row) * ldab + (size_t)k0 * 2 + cb,
              base + 32768 + it * 8192 + wid * 1024);
    }
  };

  STAGE(lds, 0);
  asm volatile("s_waitcnt vmcnt(0)" ::: "memory");
  __builtin_amdgcn_sched_barrier(0);
  __builtin_amdgcn_s_barrier();

  for (int t = 0; t < nt; ++t) {
    char* base = lds + (t & 1) * 65536;
    const char* Ab = base;
    const char* Bb = base + 32768;
    if (t + 1 < nt) STAGE(lds + ((t + 1) & 1) * 65536, t + 1);

    __builtin_amdgcn_s_setprio(1);
    bf16x8 bfr[4];
#pragma unroll
    for (int p = 0; p < 4; ++p) {
      const int ks = p >> 1, mh = p & 1;
      const int cc = ks * 64 + fg * 16;
      if (mh == 0) {
#pragma unroll
        for (int n = 0; n < 4; ++n) {
          int row = wn * 64 + n * 16 + fr;
          bfr[n] = *(const bf16x8*)(Bb + row * 128 + (cc ^ ((row & 7) << 4)));
        }
      }
      bf16x8 af[4];
#pragma unroll
      for (int i = 0; i < 4; ++i) {
        int row = wm * 128 + mh * 64 + i * 16 + fr;
        af[i] = *(const bf16x8*)(Ab + row * 128 + (cc ^ ((row & 7) << 4)));
      }
#pragma unroll
      for (int i = 0; i < 4; ++i)
#pragma unroll
        for (int n = 0; n < 4; ++n)
          acc[mh * 4 + i][n] = __builtin_amdgcn_mfma_f32_16x16x32_bf16(
              af[i], bfr[n], acc[mh * 4 + i][n], 0, 0, 0);
    }
    __builtin_amdgcn_s_setprio(0);

    __builtin_amdgcn_s_barrier();             // all waves done reading buf[t&1]
    if (t + 1 < nt)
      asm volatile("s_waitcnt vmcnt(0)" ::: "memory");  // t+1 landed (covered)
    __builtin_amdgcn_sched_barrier(0);
    __builtin_amdgcn_s_barrier();             // t+1 visible to all waves
  }

  // epilogue; D layout: col = lane&15, row = (lane>>4)*4 + reg
#pragma unroll
  for (int mi = 0; mi < 8; ++mi) {
#pragma unroll
    for (int n = 0; n < 4; ++n) {
      int cg  = n0 + wn * 64 + n * 16 + fr;
      int rgb = m0 + wm * 128 + mi * 16 + fg * 4;
      float bv = bias[cg];
#pragma unroll
      for (int r = 0; r < 4; ++r)
        Cout[(size_t)(rgb + r) * N + cg] = acc[mi][n][r] + bv;
    }
  }
}

// ---------------- gemm128: 128x128 tile, 4 waves, BK=64, counted-vmcnt pipeline --
// For grids >= 256 blocks (qkv 576, ff1 768): higher AI wins (R7: gemm64 here
// cost +73us from doubled A-traffic + 2x barrier overhead).
// EPI: 1 = bf16 out, bias+relu; 4 = qkv split (q,k -> [M][1536]; v -> vT).
template <int EPI>
__global__ __launch_bounds__(256) void gemm128_k(const __bf16* __restrict__ A,
                                                 const __bf16* __restrict__ Bt,
                                                 const float* __restrict__ bias,
                                                 const float* res,
                                                 void* Cout,
                                                 int M, int N, int K) {
  __shared__ char lds[65536];                 // 2 x (A 16KB | B 16KB)
  int tid = threadIdx.x, lane = tid & 63, wid = tid >> 6;
  int wr = wid >> 1, wc = wid & 1;
  int mt, ntile;
  tile_decode(gridDim.x, gridDim.y, mt, ntile);
  int m0 = mt * 128, n0 = ntile * 128;
  int fr = lane & 15, fg = lane >> 4;
  f32x4 acc[4][4] = {};
  const size_t ldab = (size_t)K * 2;

  auto STAGE = [&](int buf, int t) {          // 8 vmem ops/thread
    int k0 = t << 6;
    char* base = lds + buf * 32768;
#pragma unroll
    for (int it = 0; it < 4; ++it) {
      int oo  = tid * 16 + it * 4096;
      int row = oo >> 7;
      int cb  = (oo & 127) ^ ((row & 7) << 4);
      gload16((const char*)A  + (size_t)(m0 + row) * ldab + (size_t)k0 * 2 + cb,
              base + it * 4096 + wid * 1024);
      gload16((const char*)Bt + (size_t)(n0 + row) * ldab + (size_t)k0 * 2 + cb,
              base + 16384 + it * 4096 + wid * 1024);
    }
  };
  auto COMPUTE = [&](int buf) {
    char* base = lds + buf * 32768;
#pragma unroll
    for (int kk = 0; kk < 2; ++kk) {
      int cb = (kk * 64 + (fg << 4)) ^ ((lane & 7) << 4);
      bf16x8 af[4], bfr[4];
#pragma unroll
      for (int i = 0; i < 4; ++i) {
        af[i]  = *(const bf16x8*)(base         + (wr * 64 + i * 16 + fr) * 128 + cb);
        bfr[i] = *(const bf16x8*)(base + 16384 + (wc * 64 + i * 16 + fr) * 128 + cb);
      }
#pragma unroll
      for (int i = 0; i < 4; ++i)
#pragma unroll
        for (int j = 0; j < 4; ++j)
          acc[i][j] = __builtin_amdgcn_mfma_f32_16x16x32_bf16(af[i], bfr[j], acc[i][j], 0, 0, 0);
    }
  };

  int nt = K >> 6;
  STAGE(0, 0);
  STAGE(1, 1);
  asm volatile("s_waitcnt vmcnt(8)" ::: "memory");
  __builtin_amdgcn_sched_barrier(0);
  __builtin_amdgcn_s_barrier();
  int cur = 0;
  for (int t = 0; t < nt; ++t) {
    __builtin_amdgcn_s_setprio(1);
    COMPUTE(cur);
    __builtin_amdgcn_s_setprio(0);
    if (t + 1 < nt) {
      __builtin_amdgcn_s_barrier();
      if (t + 2 < nt) {
        STAGE(cur, t + 2);
        asm volatile("s_waitcnt vmcnt(8)" ::: "memory");
      } else {
        asm volatile("s_waitcnt vmcnt(0)" ::: "memory");
      }
      __builtin_amdgcn_sched_barrier(0);
      __builtin_amdgcn_s_barrier();
      cur ^= 1;
    }
  }

#pragma unroll
  for (int i = 0; i < 4; ++i) {
#pragma unroll
    for (int j = 0; j < 4; ++j) {
      int cg  = n0 + wc * 64 + j * 16 + fr;
      int rgb = m0 + wr * 64 + i * 16 + fg * 4;
      if constexpr (EPI == 4) {
        if (n0 < 1536) {                       // q,k region (block-uniform)
#pragma unroll
          for (int r = 0; r < 4; ++r)
            ((__bf16*)Cout)[(size_t)(rgb + r) * 1536 + cg] = (__bf16)acc[i][j][r];
        } else {                               // v region -> vT [768][kM]
          int d = cg - 1536;
          ushort4 pk;
          unsigned short* pp = (unsigned short*)&pk;
#pragma unroll
          for (int r = 0; r < 4; ++r) {
            __bf16 bv = (__bf16)acc[i][j][r];
            pp[r] = *(unsigned short*)&bv;
          }
          __bf16* vT = (__bf16*)const_cast<float*>(res);
          *(ushort4*)(vT + (size_t)d * kM + rgb) = pk;
        }
      } else {
        float bv = bias[cg];
#pragma unroll
        for (int r = 0; r < 4; ++r) {
          float v = acc[i][j][r] + bv;
          ((__bf16*)Cout)[(size_t)(rgb + r) * N + cg] = (__bf16)fmaxf(v, 0.f);
        }
      }
    }
  }
}

// ---------------- gemm64: 128x64 tile, 4 waves (2Mx2N), counted-vmcnt pipeline ---
// ONLY for N=768 GEMMs where gemm128's grid (192 blocks) leaves 64 CUs idle
// (R6: -190us). f32 out, bias + residual (res MAY alias Cout).
__global__ __launch_bounds__(256) void gemm64_k(const __bf16* __restrict__ A,
                                                const __bf16* __restrict__ Bt,
                                                const float* __restrict__ bias,
                                                const float* res,
                                                float* __restrict__ Cout,
                                                int M, int N, int K) {
  __shared__ char lds[49152];                 // 2 x (A 16KB | B 8KB)
  int tid = threadIdx.x, lane = tid & 63, wid = tid >> 6;
  int wr = wid >> 1, wc = wid & 1;            // wave: 64 rows x 32 cols
  int mt, ntile;
  tile_decode(gridDim.x, gridDim.y, mt, ntile);
  int m0 = mt * 128, n0 = ntile * 64;
  int fr = lane & 15, fg = lane >> 4;
  f32x4 acc[4][2] = {};
  const size_t ldab = (size_t)K * 2;

  auto STAGE = [&](int buf, int t) {          // 6 vmem ops/thread
    int k0 = t << 6;
    char* base = lds + buf * 24576;
#pragma unroll
    for (int it = 0; it < 4; ++it) {          // A: 128 rows x 128B
      int oo  = tid * 16 + it * 4096;
      int row = oo >> 7;
      int cb  = (oo & 127) ^ ((row & 7) << 4);
      gload16((const char*)A + (size_t)(m0 + row) * ldab + (size_t)k0 * 2 + cb,
              base + it * 4096 + wid * 1024);
    }
#pragma unroll
    for (int it = 0; it < 2; ++it) {          // B: 64 rows x 128B
      int oo  = tid * 16 + it * 4096;
      int row = oo >> 7;
      int cb  = (oo & 127) ^ ((row & 7) << 4);
      gload16((const char*)Bt + (size_t)(n0 + row) * ldab + (size_t)k0 * 2 + cb,
              base + 16384 + it * 4096 + wid * 1024);
    }
  };
  auto COMPUTE = [&](int buf) {
    char* base = lds + buf * 24576;
#pragma unroll
    for (int kk = 0; kk < 2; ++kk) {
      int cb = (kk * 64 + (fg << 4)) ^ ((lane & 7) << 4);
      bf16x8 af[4], bfr[2];
#pragma unroll
      for (int i = 0; i < 4; ++i)
        af[i] = *(const bf16x8*)(base + (wr * 64 + i * 16 + fr) * 128 + cb);
#pragma unroll
      for (int j = 0; j < 2; ++j)
        bfr[j] = *(const bf16x8*)(base + 16384 + (wc * 32 + j * 16 + fr) * 128 + cb);
#pragma unroll
      for (int i = 0; i < 4; ++i)
#pragma unroll
        for (int j = 0; j < 2; ++j)
          acc[i][j] = __builtin_amdgcn_mfma_f32_16x16x32_bf16(af[i], bfr[j], acc[i][j], 0, 0, 0);
    }
  };

  int nt = K >> 6;
  STAGE(0, 0);
  STAGE(1, 1);
  asm volatile("s_waitcnt vmcnt(6)" ::: "memory");
  __builtin_amdgcn_sched_barrier(0);
  __builtin_amdgcn_s_barrier();
  int cur = 0;
  for (int t = 0; t < nt; ++t) {
    __builtin_amdgcn_s_setprio(1);
    COMPUTE(cur);
    __builtin_amdgcn_s_setprio(0);
    if (t + 1 < nt) {
      __builtin_amdgcn_s_barrier();
      if (t + 2 < nt) {
        STAGE(cur, t + 2);
        asm volatile("s_waitcnt vmcnt(6)" ::: "memory");
      } else {
        asm volatile("s_waitcnt vmcnt(0)" ::: "memory");
      }
      __builtin_amdgcn_sched_barrier(0);
      __builtin_amdgcn_s_barrier();
      cur ^= 1;
    }
  }

#pragma unroll
  for (int i = 0; i < 4; ++i) {
#pragma unroll
    for (int j = 0; j < 2; ++j) {
      int cg  = n0 + wc * 32 + j * 16 + fr;
      int rgb = m0 + wr * 64 + i * 16 + fg * 4;
      float bv = bias[cg];
#pragma unroll
      for (int r = 0; r < 4; ++r) {
        float v = acc[i][j][r] + bv;
        size_t idx = (size_t)(rgb + r) * N + cg;
        Cout[idx] = v + res[idx];
      }
    }
  }
}

// ---------------- flash attention: double-buffered K/V, 1 barrier/tile, T14 ------
// qk: bf16 [4096][1536], vT: bf16 [768][4096] (cols = global rows).
// LDS 40KB -> 4 blocks/CU (3 avg resident: 768 blocks).
// qt BALANCE TABLE: work ~ qt+1; co-resident triples on a CU share x =
// blockIdx.x with band = (bb*12+hh)>>4 in {0,1,2}. Permutations
// A = evens-then-odds, B = two half-reversals, C = reversal satisfy
// A[x]+B[x]+C[x] in {22,23} for ALL x -> per-CU work 25/26 vs avg 25.5
// (~98% makespan eff; the +5/+10 rotation gave max 33 = 77%).
// Each is a bijection of 0..15 -> every (hh,bb) plane computes all 16 q-tiles.
__global__ __launch_bounds__(256) void attn_k(const __bf16* __restrict__ qk,
                                              const __bf16* __restrict__ vT,
                                              __bf16* __restrict__ optr) {
  __shared__ char lds[40960];
  int tid = threadIdx.x, lane = tid & 63, wid = tid >> 6;
  int hh = blockIdx.y, bb = blockIdx.z;
  int band = (bb * 12 + hh) >> 4;             // 0,1,2
  int xx = blockIdx.x;
  int qt;
  if (band == 0)      qt = ((xx & 7) << 1) | (xx >> 3);          // A: 0,2,..,14,1,3,..,15
  else if (band == 1) qt = (xx < 8) ? (7 - xx) : (23 - xx);      // B: 7..0,15..8
  else                qt = 15 - xx;                              // C: 15..0
  size_t rowbase = (size_t)bb * kT;
  int qr = qt * 64 + wid * 16;
  char* Psw = lds + 32768 + wid * 2048;

  bf16x8 qf[2];
  {
    const __bf16* p = qk + (rowbase + qr + (lane & 15)) * (2 * kC) + hh * 64 + ((lane >> 4) * 8);
    qf[0] = *(const bf16x8*)p;
    qf[1] = *(const bf16x8*)(p + 32);
  }
  f32x4 oacc[4] = {};
  float mrun[4] = {kNEG, kNEG, kNEG, kNEG};
  float lrun[4] = {0.f, 0.f, 0.f, 0.f};

  bf16x8 kr[2], vr[2];
  auto LOADT = [&](int st) {                  // global -> regs (pre-swizzled slots)
    int s0 = st * 64;
#pragma unroll
    for (int it = 0; it < 2; ++it) {
      int oo  = tid * 16 + it * 4096;
      int row = oo >> 7;
      int cb  = (oo & 127) ^ ((row & 7) << 4);
      kr[it] = *(const bf16x8*)((const char*)qk +
                 ((rowbase + s0 + row) * (2 * kC) + kC + hh * 64) * 2 + cb);
      vr[it] = *(const bf16x8*)((const char*)vT +
                 ((size_t)(hh * 64 + row) * kM + rowbase + s0) * 2 + cb);
    }
  };
  auto WRITET = [&](int buf) {                // regs -> LDS[buf]
    char* b = lds + buf * 16384;
#pragma unroll
    for (int it = 0; it < 2; ++it) {
      int oo = tid * 16 + it * 4096;
      *(bf16x8*)(b + oo)        = kr[it];
      *(bf16x8*)(b + 8192 + oo) = vr[it];
    }
  };

  LOADT(0);
  WRITET(0);
  if (qt >= 1) LOADT(1);

  for (int st = 0; st <= qt; ++st) {
    int cur = st & 1;
    char* kb = lds + cur * 16384;
    char* vb = kb + 8192;
    __syncthreads();                          // prev compute done; own writes drained
    if (st + 1 <= qt) {
      WRITET(cur ^ 1);                        // regs hold tile st+1
      if (st + 2 <= qt) LOADT(st + 2);        // issue early: full tile of cover
    }

    int s0 = st * 64;
    // S = Q K^T
    f32x4 sacc[4] = {};
#pragma unroll
    for (int kk = 0; kk < 2; ++kk) {
      int cb = (kk * 64 + ((lane >> 4) << 4)) ^ ((lane & 7) << 4);
#pragma unroll
      for (int j = 0; j < 4; ++j) {
        bf16x8 kf = *(const bf16x8*)(kb + (j * 16 + (lane & 15)) * 128 + cb);
        sacc[j] = __builtin_amdgcn_mfma_f32_16x16x32_bf16(qf[kk], kf, sacc[j], 0, 0, 0);
      }
    }

    // online softmax (row = qr + (lane>>4)*4 + r, col = s0 + j*16 + (lane&15))
    float pv[4][4], vm[4] = {kNEG, kNEG, kNEG, kNEG};
#pragma unroll
    for (int j = 0; j < 4; ++j) {
      int scol = s0 + j * 16 + (lane & 15);
#pragma unroll
      for (int r = 0; r < 4; ++r) {
        int qrow = qr + (lane >> 4) * 4 + r;
        float sv = sacc[j][r] * 0.125f;
        if (scol > qrow) sv = kNEG;
        pv[j][r] = sv;
        vm[r] = fmaxf(vm[r], sv);
      }
    }
#pragma unroll
    for (int r = 0; r < 4; ++r) {
      float v = vm[r];
      v = fmaxf(v, __shfl_xor(v, 1, 64)); v = fmaxf(v, __shfl_xor(v, 2, 64));
      v = fmaxf(v, __shfl_xor(v, 4, 64)); v = fmaxf(v, __shfl_xor(v, 8, 64));
      float mnew = fmaxf(mrun[r], v);
      float sc = __expf(mrun[r] - mnew);
      mrun[r] = mnew;
      lrun[r] *= sc;
      oacc[0][r] *= sc; oacc[1][r] *= sc; oacc[2][r] *= sc; oacc[3][r] *= sc;
      float rsum = 0.f;
#pragma unroll
      for (int j = 0; j < 4; ++j) {
        float p = __expf(pv[j][r] - mnew);
        pv[j][r] = p;
        rsum += p;
      }
      rsum += __shfl_xor(rsum, 1, 64); rsum += __shfl_xor(rsum, 2, 64);
      rsum += __shfl_xor(rsum, 4, 64); rsum += __shfl_xor(rsum, 8, 64);
      lrun[r] += rsum;
    }

    // P (D-layout regs) -> per-wave LDS (swizzled) as A-operand
#pragma unroll
    for (int j = 0; j < 4; ++j)
#pragma unroll
      for (int r = 0; r < 4; ++r) {
        int rloc = (lane >> 4) * 4 + r;
        int cbyt = (2 * (j * 16 + (lane & 15))) ^ ((rloc & 7) << 4);
        *(__bf16*)(Psw + rloc * 128 + cbyt) = (__bf16)pv[j][r];
      }

    // O += P @ V
#pragma unroll
    for (int kk = 0; kk < 2; ++kk) {
      int cb = (kk * 64 + ((lane >> 4) << 4)) ^ ((lane & 7) << 4);
      bf16x8 pf = *(const bf16x8*)(Psw + (lane & 15) * 128 + cb);
#pragma unroll
      for (int j = 0; j < 4; ++j) {
        bf16x8 vf = *(const bf16x8*)(vb + (j * 16 + (lane & 15)) * 128 + cb);
        oacc[j] = __builtin_amdgcn_mfma_f32_16x16x32_bf16(pf, vf, oacc[j], 0, 0, 0);
      }
    }
  }

#pragma unroll
  for (int r = 0; r < 4; ++r) {
    float inv = lrun[r] > 0.f ? 1.f / lrun[r] : 0.f;
#pragma unroll
    for (int j = 0; j < 4; ++j) {
      int cg = hh * 64 + j * 16 + (lane & 15);
      int rg = qr + (lane >> 4) * 4 + r;
      optr[(rowbase + rg) * kC + cg] = (__bf16)(oacc[j][r] * inv);
    }
  }
}

// ---------------- host ----------------
extern "C" void kernel_launch(void* const* d_in, const int* in_sizes, int n_in,
                              void* d_out, int out_size, void* d_ws, size_t ws_size,
                              hipStream_t stream) {
  (void)in_sizes; (void)n_in; (void)out_size; (void)ws_size;
  const int*   tokens  = (const int*)  d_in[0];
  const float* tok_emb = (const float*)d_in[1];
  const float* pos_emb = (const float*)d_in[2];
  const float* ln1_g   = (const float*)d_in[3];
  const float* ln1_b   = (const float*)d_in[4];
  const float* wq      = (const float*)d_in[5];
  const float* wk      = (const float*)d_in[6];
  const float* wv      = (const float*)d_in[7];
  const float* wo      = (const float*)d_in[8];
  const float* bo      = (const float*)d_in[9];
  const float* ln2_g   = (const float*)d_in[10];
  const float* ln2_b   = (const float*)d_in[11];
  const float* w1      = (const float*)d_in[12];
  const float* b1      = (const float*)d_in[13];
  const float* w2      = (const float*)d_in[14];
  const float* b2      = (const float*)d_in[15];
  const float* lnf_g   = (const float*)d_in[16];
  const float* lnf_b   = (const float*)d_in[17];
  const float* lm_w    = (const float*)d_in[18];
  const float* lm_b    = (const float*)d_in[19];
  float* out = (float*)d_out;

  char* ws = (char*)d_ws;
  size_t off = 0;
  auto alloc = [&](size_t bytes) -> char* {
    char* p = ws + off; off += (bytes + 255) & ~(size_t)255; return p;
  };
  float*  x    = (float*) alloc((size_t)kM * kC * 4);             // 12.6 MB
  __bf16* h    = (__bf16*)alloc((size_t)kM * kC * 2);             // 6.3 MB
  __bf16* qkvT = (__bf16*)alloc((size_t)kL * 3 * kC * kC * 2);    // 21.2 MB
  __bf16* woT  = (__bf16*)alloc((size_t)kL * kC * kC * 2);        //  7.1 MB
  __bf16* w1T  = (__bf16*)alloc((size_t)kL * kC * kF * 2);        // 28.3 MB
  __bf16* w2T  = (__bf16*)alloc((size_t)kL * kC * kF * 2);        // 28.3 MB
  __bf16* qkb  = (__bf16*)alloc((size_t)kM * 2 * kC * 2);         // 12.6 MB
  __bf16* vTb  = (__bf16*)alloc((size_t)kC * kM * 2);             // 6.3 MB
  __bf16* ob   = (__bf16*)alloc((size_t)kM * kC * 2);             // 6.3 MB
  __bf16* ffb  = (__bf16*)alloc((size_t)kM * kF * 2);             // 25.2 MB
  __bf16* lmwT = qkb;  // lm head transpose aliases qkb..ffb (50.4 >= 49.2 MB)

  dim3 blk(256), blk512(512);
  convT3_k<<<dim3(kC/32, kC/32, 3*kL), blk, 0, stream>>>(wq, wk, wv, qkvT);
  convT_k<<<dim3(kC/32, kC/32, kL), blk, 0, stream>>>(wo, woT, kC, kC, (size_t)kC*kC, (size_t)kC*kC);
  convT_k<<<dim3(kF/32, kC/32, kL), blk, 0, stream>>>(w1, w1T, kC, kF, (size_t)kC*kF, (size_t)kC*kF);
  convT_k<<<dim3(kC/32, kF/32, kL), blk, 0, stream>>>(w2, w2T, kF, kC, (size_t)kC*kF, (size_t)kC*kF);

  embed_k<<<kM, 192, 0, stream>>>(tokens, tok_emb, pos_emb, x);

  for (int l = 0; l < kL; ++l) {
    ln_k<<<kM, 192, 0, stream>>>(x, ln1_g + l*kC, ln1_b + l*kC, h);
    // q,k -> qkb [4096][1536]; v -> vTb [768][4096] (transposed epilogue); 576 blk
    gemm128_k<4><<<dim3(3*kC/128, kM/128), blk, 0, stream>>>(
        h, qkvT + (size_t)l*3*kC*kC, nullptr, (const float*)vTb, qkb, kM, 3*kC, kC);
    attn_k<<<dim3(kT/64, kH, kB), blk, 0, stream>>>(qkb, vTb, ob);
    // x = o @ wo + bo + x (in-place residual), 128x64 tiles: 384 blocks
    gemm64_k<<<dim3(kC/64, kM/128), blk, 0, stream>>>(ob, woT + (size_t)l*kC*kC, bo + l*kC, x, x, kM, kC, kC);
    ln_k<<<kM, 192, 0, stream>>>(x, ln2_g + l*kC, ln2_b + l*kC, h);
    // ff = relu(h @ w1 + b1); 768 blocks
    gemm128_k<1><<<dim3(kF/128, kM/128), blk, 0, stream>>>(h, w1T + (size_t)l*kC*kF, b1 + l*kF, nullptr, ffb, kM, kF, kC);
    // x = ff @ w2 + b2 + x, 128x64 tiles: 384 blocks
    gemm64_k<<<dim3(kC/64, kM/128), blk, 0, stream>>>(ffb, w2T + (size_t)l*kC*kF, b2 + l*kC, x, x, kM, kC, kF);
  }
  convT_k<<<dim3(kV/32, kC/32, 1), blk, 0, stream>>>(lm_w, lmwT, kC, kV, 0, 0);
  ln_k<<<kM, 192, 0, stream>>>(x, lnf_g, lnf_b, h);
  // logits = h @ lm_w + lm_b  (2-barrier whole-tile 256² pipeline, fp32 out)
  gemmHD_k<<<dim3(kV/256, kM/256), blk512, 0, stream>>>(h, lmwT, lm_b, out, kM, kV, kC);
}